// Round 11
// baseline (221.185 us; speedup 1.0000x reference)
//
#include <hip/hip_runtime.h>

typedef __attribute__((ext_vector_type(8))) short s8v;   // 8 bf16 (4 VGPRs) MFMA A/B frag
typedef __attribute__((ext_vector_type(4))) float f4v;   // MFMA C/D frag

#define QSC (0.17677669529663687f * 1.4426950408889634f)  // 1/sqrt(32) * log2(e), folded into q

__device__ __forceinline__ unsigned short f2bf(float x) {
    unsigned u = __float_as_uint(x);
    return (unsigned short)((u + 0x7fffu + ((u >> 16) & 1u)) >> 16);  // RNE
}
__device__ __forceinline__ float bf2f(unsigned short h) {
    return __uint_as_float(((unsigned)h) << 16);
}
// truncation pack (round-toward-zero; P>=0 and O/L use the same truncated P)
__device__ __forceinline__ unsigned trunc2(float a, float b) {
    return (__float_as_uint(b) & 0xffff0000u) | (__float_as_uint(a) >> 16);
}

// One-shot weight prep (unchanged, verified r7-r10)
__global__ __launch_bounds__(256) void wconv_kernel(
    const float* __restrict__ wqk, const float* __restrict__ sqk, const float* __restrict__ bqk,
    const float* __restrict__ wv,  const float* __restrict__ sv,  const float* __restrict__ bv,
    const float* __restrict__ wprj, const float* __restrict__ sprj,
    const float* __restrict__ wm1, const float* __restrict__ sm1, const float* __restrict__ bm1,
    const float* __restrict__ wm2, const float* __restrict__ sm2,
    unsigned short* __restrict__ Wqkv, unsigned short* __restrict__ Wp,
    unsigned short* __restrict__ Wm1,  unsigned short* __restrict__ Wm2,
    float* __restrict__ bpad, float* __restrict__ bqv)
{
    int i = blockIdx.x * 256 + threadIdx.x;
    if (i < 196608) {                       // Wqkv [768][256]
        int o = i >> 8, c = i & 255;
        float w;
        if (o < 512) { float f = ((o & 127) < 64) ? QSC : 1.f; w = wqk[i] * sqk[o] * f; }
        else          w = wv[(o - 512) * 256 + c] * sv[o - 512];
        Wqkv[i] = f2bf(w);
    } else if (i < 262144) {                // w_proj [256][256]
        int j = i - 196608; int o = j >> 8; Wp[j] = f2bf(wprj[j] * sprj[o]);
    } else if (i < 360448) {                // w_m1 [384pad][256]
        int j = i - 262144; int o = j >> 8, c = j & 255;
        Wm1[j] = (o < 307) ? f2bf(wm1[o * 256 + c] * sm1[o]) : (unsigned short)0;
    } else if (i < 458752) {                // w_m2 [256][384pad]
        int j = i - 360448; int o = j / 384, c = j - o * 384;
        Wm2[j] = (c < 307) ? f2bf(wm2[o * 307 + c] * sm2[o]) : (unsigned short)0;
    } else if (i < 459136) {                // b_m1 padded to 384
        int j = i - 458752; bpad[j] = (j < 307) ? bm1[j] : 0.f;
    } else if (i < 459904) {                // bqv[768]
        int j = i - 459136;
        bqv[j] = (j < 512) ? (bqk[j] * (((j & 127) < 64) ? QSC : 1.f)) : bv[j - 512];
    }
}

// Fused transpose + qkv GEMM; v-channels additionally written transposed to
// vT[b][c][4096] bf16 for the attention's direct-global V fragments.
__global__ __launch_bounds__(256) void mmqkv_kernel(
    const float* __restrict__ X, const unsigned short* __restrict__ Wb,
    const float* __restrict__ bi, unsigned short* __restrict__ Yb,
    unsigned short* __restrict__ vT)
{
    __shared__ unsigned short Ap[64][40];
    __shared__ unsigned short Wt[128][40];
    const int tid = threadIdx.x, lane = tid & 63, wv = tid >> 6;
    const int lo4 = lane & 15, quad = lane >> 4;
    const int p0 = blockIdx.x * 64, o0 = blockIdx.y * 128, bB = blockIdx.z;
    const int ph = (wv & 1) * 32, oh = (wv >> 1) * 64;
    const int c2 = tid & 15, pg = tid >> 4;
    const int oW0 = tid >> 2, oW1 = (tid + 256) >> 2;
    const int cW = (tid & 3) * 8;
    const float* xb = X + (size_t)bB * 256 * 4096;

    f4v acc[4][2];
    #pragma unroll
    for (int i = 0; i < 4; i++)
        #pragma unroll
        for (int j = 0; j < 2; j++)
            acc[i][j] = (f4v){0.f, 0.f, 0.f, 0.f};

    float4 fa = *(const float4*)&xb[(size_t)(2 * c2) * 4096 + p0 + pg * 4];
    float4 fb = *(const float4*)&xb[(size_t)(2 * c2 + 1) * 4096 + p0 + pg * 4];
    uint4 wReg0 = *(const uint4*)(Wb + (size_t)(o0 + oW0) * 256 + cW);
    uint4 wReg1 = *(const uint4*)(Wb + (size_t)(o0 + oW1) * 256 + cW);

    for (int kc = 0; kc < 8; kc++) {
        __syncthreads();
        {
            float av[4] = {fa.x, fa.y, fa.z, fa.w};
            float bv2[4] = {fb.x, fb.y, fb.z, fb.w};
            #pragma unroll
            for (int i = 0; i < 4; i++)
                *(unsigned*)&Ap[pg * 4 + i][2 * c2] =
                    (unsigned)f2bf(av[i]) | ((unsigned)f2bf(bv2[i]) << 16);
        }
        *(uint4*)&Wt[oW0][cW] = wReg0;
        *(uint4*)&Wt[oW1][cW] = wReg1;
        __syncthreads();
        if (kc < 7) {
            int k1 = (kc + 1) * 32;
            fa = *(const float4*)&xb[(size_t)(k1 + 2 * c2) * 4096 + p0 + pg * 4];
            fb = *(const float4*)&xb[(size_t)(k1 + 2 * c2 + 1) * 4096 + p0 + pg * 4];
            wReg0 = *(const uint4*)(Wb + (size_t)(o0 + oW0) * 256 + k1 + cW);
            wReg1 = *(const uint4*)(Wb + (size_t)(o0 + oW1) * 256 + k1 + cW);
        }
        s8v af[4], bx[2];
        #pragma unroll
        for (int of = 0; of < 4; of++)
            af[of] = *(const s8v*)&Wt[oh + of * 16 + lo4][quad * 8];
        #pragma unroll
        for (int pf = 0; pf < 2; pf++)
            bx[pf] = *(const s8v*)&Ap[ph + pf * 16 + lo4][quad * 8];
        #pragma unroll
        for (int of = 0; of < 4; of++)
            #pragma unroll
            for (int pf = 0; pf < 2; pf++)
                acc[of][pf] = __builtin_amdgcn_mfma_f32_16x16x32_bf16(af[of], bx[pf], acc[of][pf], 0, 0, 0);
    }
    #pragma unroll
    for (int of = 0; of < 4; of++) {
        int ob = o0 + oh + of * 16 + quad * 4;
        float4 bb = *(const float4*)&bi[ob];
        float bbv[4] = {bb.x, bb.y, bb.z, bb.w};
        #pragma unroll
        for (int pf = 0; pf < 2; pf++) {
            int p = p0 + ph + pf * 16 + lo4;
            size_t row = (size_t)bB * 4096 + p;
            unsigned short b4[4];
            #pragma unroll
            for (int r = 0; r < 4; r++) b4[r] = f2bf(acc[of][pf][r] + bbv[r]);
            *(ushort4*)&Yb[row * 768 + ob] = *(ushort4*)b4;
            if (ob >= 512) {   // v channels: transposed copy for attention
                #pragma unroll
                for (int r = 0; r < 4; r++)
                    vT[((size_t)(bB * 256 + ob - 512 + r)) * 4096 + p] = b4[r];
            }
        }
    }
}

// 64p x 128o tile GEMM (core verified r4-r10) with register double-buffer.
__global__ __launch_bounds__(256) void mm_kernel(
    const unsigned short* __restrict__ A, int Kpad,
    const unsigned short* __restrict__ Wb,
    const float* __restrict__ bi, const float* __restrict__ R,
    const float* __restrict__ Rt, const unsigned short* __restrict__ Rb,
    unsigned short* __restrict__ Yb, int SYb, float* __restrict__ Yf,
    float* __restrict__ Yt, int doSilu)
{
    __shared__ unsigned short Ap[64][40];
    __shared__ unsigned short Wt[128][40];
    const int tid = threadIdx.x, lane = tid & 63, wv = tid >> 6;
    const int lo4 = lane & 15, quad = lane >> 4;
    const int p0 = blockIdx.x * 64, o0 = blockIdx.y * 128, bB = blockIdx.z;
    const int ph = (wv & 1) * 32, oh = (wv >> 1) * 64;
    const size_t abase = (size_t)bB * 4096 * Kpad;
    const int pA = tid >> 2, cA = (tid & 3) * 8;
    const int oW0 = tid >> 2, oW1 = (tid + 256) >> 2;
    const int cW = (tid & 3) * 8;

    f4v acc[4][2];
    #pragma unroll
    for (int i = 0; i < 4; i++)
        #pragma unroll
        for (int j = 0; j < 2; j++)
            acc[i][j] = (f4v){0.f, 0.f, 0.f, 0.f};

    const int nK = Kpad / 32;
    uint4 aReg = *(const uint4*)(A + abase + (size_t)(p0 + pA) * Kpad + cA);
    uint4 wReg0 = *(const uint4*)(Wb + (size_t)(o0 + oW0) * Kpad + cW);
    uint4 wReg1 = *(const uint4*)(Wb + (size_t)(o0 + oW1) * Kpad + cW);

    for (int kc = 0; kc < nK; kc++) {
        __syncthreads();
        *(uint4*)&Ap[pA][cA] = aReg;
        *(uint4*)&Wt[oW0][cW] = wReg0;
        *(uint4*)&Wt[oW1][cW] = wReg1;
        __syncthreads();
        if (kc + 1 < nK) {
            int k1 = (kc + 1) * 32;
            aReg  = *(const uint4*)(A + abase + (size_t)(p0 + pA) * Kpad + k1 + cA);
            wReg0 = *(const uint4*)(Wb + (size_t)(o0 + oW0) * Kpad + k1 + cW);
            wReg1 = *(const uint4*)(Wb + (size_t)(o0 + oW1) * Kpad + k1 + cW);
        }
        s8v af[4], bx[2];
        #pragma unroll
        for (int of = 0; of < 4; of++)
            af[of] = *(const s8v*)&Wt[oh + of * 16 + lo4][quad * 8];
        #pragma unroll
        for (int pf = 0; pf < 2; pf++)
            bx[pf] = *(const s8v*)&Ap[ph + pf * 16 + lo4][quad * 8];
        #pragma unroll
        for (int of = 0; of < 4; of++)
            #pragma unroll
            for (int pf = 0; pf < 2; pf++)
                acc[of][pf] = __builtin_amdgcn_mfma_f32_16x16x32_bf16(af[of], bx[pf], acc[of][pf], 0, 0, 0);
    }
    #pragma unroll
    for (int of = 0; of < 4; of++) {
        int ob = o0 + oh + of * 16 + quad * 4;
        float4 bb = *(const float4*)&bi[ob];
        float bbv[4] = {bb.x, bb.y, bb.z, bb.w};
        #pragma unroll
        for (int pf = 0; pf < 2; pf++) {
            int p = p0 + ph + pf * 16 + lo4;
            size_t row = (size_t)bB * 4096 + p;
            float y[4];
            #pragma unroll
            for (int r = 0; r < 4; r++) y[r] = acc[of][pf][r] + bbv[r];
            if (doSilu) {
                #pragma unroll
                for (int r = 0; r < 4; r++) y[r] = y[r] / (1.f + __expf(-y[r]));
            }
            if (R) {
                float4 rr = *(const float4*)&R[row * 256 + ob];
                y[0] += rr.x; y[1] += rr.y; y[2] += rr.z; y[3] += rr.w;
            }
            if (Rt) {
                #pragma unroll
                for (int r = 0; r < 4; r++)
                    y[r] += Rt[((size_t)(bB * 256 + ob + r)) * 4096 + p];
            }
            if (Rb) {
                ushort4 rb = *(const ushort4*)&Rb[row * 256 + ob];
                y[0] += bf2f(rb.x); y[1] += bf2f(rb.y); y[2] += bf2f(rb.z); y[3] += bf2f(rb.w);
            }
            if (Yf) *(float4*)&Yf[row * 256 + ob] = make_float4(y[0], y[1], y[2], y[3]);
            if (Yb) {
                ushort4 b4;
                b4.x = f2bf(y[0]); b4.y = f2bf(y[1]); b4.z = f2bf(y[2]); b4.w = f2bf(y[3]);
                *(ushort4*)&Yb[row * SYb + ob] = b4;
            }
            if (Yt) {
                #pragma unroll
                for (int r = 0; r < 4; r++)
                    Yt[((size_t)(bB * 256 + ob + r)) * 4096 + p] = y[r];
            }
        }
    }
}

// MFMA area-attention: fully barrier-free, zero V staging (direct-global V frags
// from vT), per-wave P LDS only (18.4 KB -> 8 blocks/CU). K prefetch, ones-MFMA L,
// direct O stores, XCD swizzle — all from the passing r10.
__global__ __launch_bounds__(256) void attn_kernel(
    const unsigned short* __restrict__ qv, const unsigned short* __restrict__ vT,
    unsigned short* __restrict__ Opart, float* __restrict__ Lpart)
{
    __shared__ unsigned short Pq[4][32][72];   // per-wave P [q][m]
    const int tid = threadIdx.x;
    const int w = tid >> 6, lane = tid & 63;
    const int lo4 = lane & 15, quad = lane >> 4;
    const int n0 = blockIdx.z * 128;
    const int h = blockIdx.y;
    const int z = blockIdx.x;
    const int ba = z >> 2, spl = z & 3;
    const int bB = ba >> 2, g = ba & 3;
    const int mbase = spl * 256;

    s8v qf[2];
    #pragma unroll
    for (int qc = 0; qc < 2; qc++)
        qf[qc] = *(const s8v*)(qv + ((size_t)(bB * 4096 + quad * 1024 + n0 + w * 32 + qc * 16 + lo4)) * 768 + g * 128 + h * 8);
    const unsigned short* kbase = qv + ((size_t)(bB * 4096 + quad * 1024)) * 768 + g * 128 + 64 + h * 8;
    const unsigned short* vbase = vT + ((size_t)(bB * 256 + g * 64 + h * 8)) * 4096 + mbase;

    f4v oacc[2][2], Lacc[2];
    #pragma unroll
    for (int i = 0; i < 2; i++) {
        Lacc[i] = (f4v){0.f, 0.f, 0.f, 0.f};
        #pragma unroll
        for (int j = 0; j < 2; j++)
            oacc[i][j] = (f4v){0.f, 0.f, 0.f, 0.f};
    }
    s8v ones;
    #pragma unroll
    for (int j = 0; j < 8; j++) ones[j] = (short)0x3F80;   // bf16 1.0

    s8v kf[4];
    #pragma unroll
    for (int mf = 0; mf < 4; mf++)
        kf[mf] = *(const s8v*)(kbase + (size_t)(mbase + mf * 16 + lo4) * 768);

    for (int sc = 0; sc < 4; sc++) {
        s8v kfn[4];
        if (sc < 3) {
            #pragma unroll
            for (int mf = 0; mf < 4; mf++)
                kfn[mf] = *(const s8v*)(kbase + (size_t)(mbase + (sc + 1) * 64 + mf * 16 + lo4) * 768);
        }
        f4v sT[4][2];
        #pragma unroll
        for (int mf = 0; mf < 4; mf++)
            #pragma unroll
            for (int qc = 0; qc < 2; qc++)
                sT[mf][qc] = __builtin_amdgcn_mfma_f32_16x16x32_bf16(kf[mf], qf[qc], (f4v){0.f, 0.f, 0.f, 0.f}, 0, 0, 0);
        #pragma unroll
        for (int qc = 0; qc < 2; qc++) {
            #pragma unroll
            for (int mf = 0; mf < 4; mf++) {
                float p0v = exp2f(sT[mf][qc][0]);
                float p1v = exp2f(sT[mf][qc][1]);
                float p2v = exp2f(sT[mf][qc][2]);
                float p3v = exp2f(sT[mf][qc][3]);
                uint2 pk;
                pk.x = trunc2(p0v, p1v);
                pk.y = trunc2(p2v, p3v);
                *(uint2*)&Pq[w][qc * 16 + lo4][mf * 16 + quad * 4] = pk;
            }
        }
        #pragma unroll
        for (int mc = 0; mc < 2; mc++) {
            s8v pfr[2];
            #pragma unroll
            for (int qc = 0; qc < 2; qc++)
                pfr[qc] = *(const s8v*)&Pq[w][qc * 16 + lo4][mc * 32 + quad * 8];
            #pragma unroll
            for (int df = 0; df < 2; df++) {
                int dd = df * 16 + lo4;   // d' -> (channel dd&7, pos-block dd>>3)
                s8v vfr = *(const s8v*)(vbase + (size_t)(dd & 7) * 4096 + (dd >> 3) * 1024
                                        + sc * 64 + mc * 32 + quad * 8);
                #pragma unroll
                for (int qc = 0; qc < 2; qc++)
                    oacc[df][qc] = __builtin_amdgcn_mfma_f32_16x16x32_bf16(vfr, pfr[qc], oacc[df][qc], 0, 0, 0);
            }
            #pragma unroll
            for (int qc = 0; qc < 2; qc++)
                Lacc[qc] = __builtin_amdgcn_mfma_f32_16x16x32_bf16(ones, pfr[qc], Lacc[qc], 0, 0, 0);
        }
        #pragma unroll
        for (int mf = 0; mf < 4; mf++) kf[mf] = kfn[mf];
    }
    if (quad == 0) {
        size_t lb = (((size_t)(spl * 2 + bB) * 4 + g) * 8 + h) * 1024 + n0 + w * 32;
        Lpart[lb + lo4] = Lacc[0][0];
        Lpart[lb + 16 + lo4] = Lacc[1][0];
    }
    #pragma unroll
    for (int qc = 0; qc < 2; qc++)
        #pragma unroll
        for (int df = 0; df < 2; df++) {
            int pb = df * 2 + (quad >> 1);
            uint2 ov;
            ov.x = trunc2(oacc[df][qc][0], oacc[df][qc][1]);
            ov.y = trunc2(oacc[df][qc][2], oacc[df][qc][3]);
            *(uint2*)(Opart + ((size_t)(spl * 2 + bB) * 4096 + pb * 1024 + n0 + w * 32 + qc * 16 + lo4) * 256
                      + g * 64 + h * 8 + (quad & 1) * 4) = ov;
        }
}

// Fused combine + depthwise pe (unchanged, verified r8-r10)
__global__ __launch_bounds__(256) void attpe_kernel(
    const unsigned short* __restrict__ Opart, const float* __restrict__ Lpart,
    const unsigned short* __restrict__ qv, const float* __restrict__ wpe,
    const float* __restrict__ spe, const float* __restrict__ bpe,
    unsigned short* __restrict__ attpe)
{
    int idx = blockIdx.x * 256 + threadIdx.x;   // 2*4096*32
    int cg = (idx & 31) * 8;
    int p = (idx >> 5) & 4095;
    int bB = idx >> 17;
    int g = cg >> 6, h = (cg >> 3) & 7;
    int na = p & 1023;
    float L = 0.f;
    float o[8] = {};
    #pragma unroll
    for (int spl = 0; spl < 4; spl++) {
        L += Lpart[(((size_t)(spl * 2 + bB) * 4 + g) * 8 + h) * 1024 + na];
        uint4 v = *(const uint4*)(Opart + ((size_t)(spl * 2 + bB) * 4096 + p) * 256 + cg);
        unsigned short tmp[8]; *(uint4*)tmp = v;
        #pragma unroll
        for (int j = 0; j < 8; j++) o[j] += bf2f(tmp[j]);
    }
    float inv = 1.f / L;
    int hh = p >> 6, ww = p & 63;
    float pe[8] = {};
    for (int di = -1; di <= 1; di++) {
        int h2 = hh + di;
        if (h2 < 0 || h2 > 63) continue;
        for (int dj = -1; dj <= 1; dj++) {
            int w2 = ww + dj;
            if (w2 < 0 || w2 > 63) continue;
            uint4 vv = *(const uint4*)(qv + ((size_t)(bB * 4096 + h2 * 64 + w2)) * 768 + 512 + cg);
            unsigned short tmp[8]; *(uint4*)tmp = vv;
            int k = (di + 1) * 3 + (dj + 1);
            #pragma unroll
            for (int j = 0; j < 8; j++)
                pe[j] = fmaf(bf2f(tmp[j]), wpe[(cg + j) * 9 + k], pe[j]);
        }
    }
    unsigned short ob[8];
    #pragma unroll
    for (int j = 0; j < 8; j++)
        ob[j] = f2bf(o[j] * inv + pe[j] * spe[cg + j] + bpe[cg + j]);
    *(uint4*)(attpe + ((size_t)(bB * 4096 + p)) * 256 + cg) = *(uint4*)ob;
}

extern "C" void kernel_launch(void* const* d_in, const int* in_sizes, int n_in,
                              void* d_out, int out_size, void* d_ws, size_t ws_size,
                              hipStream_t stream)
{
    const float* x      = (const float*)d_in[0];
    const float* w_qk   = (const float*)d_in[1];
    const float* s_qk   = (const float*)d_in[2];
    const float* b_qk   = (const float*)d_in[3];
    const float* w_v    = (const float*)d_in[4];
    const float* s_v    = (const float*)d_in[5];
    const float* b_v    = (const float*)d_in[6];
    const float* w_pe   = (const float*)d_in[7];
    const float* s_pe   = (const float*)d_in[8];
    const float* b_pe   = (const float*)d_in[9];
    const float* w_proj = (const float*)d_in[10];
    const float* s_proj = (const float*)d_in[11];
    const float* b_proj = (const float*)d_in[12];
    const float* w_m1   = (const float*)d_in[13];
    const float* s_m1   = (const float*)d_in[14];
    const float* b_m1   = (const float*)d_in[15];
    const float* w_m2   = (const float*)d_in[16];
    const float* s_m2   = (const float*)d_in[17];
    const float* b_m2   = (const float*)d_in[18];
    float* out = (float*)d_out;

    const size_t NA = (size_t)2 * 4096 * 256;     // 2,097,152
    unsigned short* attpe = (unsigned short*)d_ws;  // bf16 [b][p][256]
    unsigned short* qv   = attpe + NA;            // bf16 [b][p][768]
    unsigned short* Opart = qv + 3 * NA;          // bf16 [4][b][p][256]
    unsigned short* x1b  = Opart;                 // alias: Opart dead after attpe
    unsigned short* mhb  = Opart + NA;            // alias  [b][p][384]
    float* Lpart = (float*)(Opart + 4 * NA);      // fp32 [4][b][4][8][1024]
    unsigned short* Wqkv = (unsigned short*)(Lpart + 262144);
    unsigned short* Wp   = Wqkv + 196608;
    unsigned short* Wm1  = Wp + 65536;
    unsigned short* Wm2  = Wm1 + 98304;
    float* bpad = (float*)(Wm2 + 98304);
    float* bqv  = bpad + 384;
    unsigned short* vT = (unsigned short*)(bqv + 768);   // bf16 [b][256][4096]

    dim3 blk(256);
    wconv_kernel<<<dim3(1797), blk, 0, stream>>>(
        w_qk, s_qk, b_qk, w_v, s_v, b_v, w_proj, s_proj,
        w_m1, s_m1, b_m1, w_m2, s_m2, Wqkv, Wp, Wm1, Wm2, bpad, bqv);

    // fused transpose + qkv = conv1x1(x, [w_qk; w_v]); v also written transposed
    mmqkv_kernel<<<dim3(64, 6, 2), blk, 0, stream>>>(x, Wqkv, bqv, qv, vT);

    attn_kernel<<<dim3(32, 8, 8), blk, 0, stream>>>(qv, vT, Opart, Lpart);
    attpe_kernel<<<dim3(1024), blk, 0, stream>>>(Opart, Lpart, qv, w_pe, s_pe, b_pe, attpe);

    // x1b = bf16(x + proj(att + pe))   (residual read transposed from x)
    mm_kernel<<<dim3(64, 2, 2), blk, 0, stream>>>(
        attpe, 256, Wp, b_proj, nullptr, x, nullptr, x1b, 256, nullptr, nullptr, 0);
    // mh = silu(m1(x1)), padded to 384
    mm_kernel<<<dim3(64, 3, 2), blk, 0, stream>>>(
        x1b, 256, Wm1, bpad, nullptr, nullptr, nullptr, mhb, 384, nullptr, nullptr, 1);
    // out = x1 + m2(mh), stored transposed to [b][256][4096]; residual from x1b bf16
    mm_kernel<<<dim3(64, 2, 2), blk, 0, stream>>>(
        mhb, 384, Wm2, b_m2, nullptr, nullptr, x1b, nullptr, 0, nullptr, out, 0);
}

// Round 12
// 212.618 us; speedup vs baseline: 1.0403x; 1.0403x over previous
//
#include <hip/hip_runtime.h>

typedef __attribute__((ext_vector_type(8))) short s8v;   // 8 bf16 (4 VGPRs) MFMA A/B frag
typedef __attribute__((ext_vector_type(4))) float f4v;   // MFMA C/D frag

#define QSC (0.17677669529663687f * 1.4426950408889634f)  // 1/sqrt(32) * log2(e), folded into q

__device__ __forceinline__ unsigned short f2bf(float x) {
    unsigned u = __float_as_uint(x);
    return (unsigned short)((u + 0x7fffu + ((u >> 16) & 1u)) >> 16);  // RNE
}
__device__ __forceinline__ float bf2f(unsigned short h) {
    return __uint_as_float(((unsigned)h) << 16);
}
// truncation pack (round-toward-zero; P>=0 and O/L use the same truncated P)
__device__ __forceinline__ unsigned trunc2(float a, float b) {
    return (__float_as_uint(b) & 0xffff0000u) | (__float_as_uint(a) >> 16);
}

// One-shot weight prep (unchanged, verified r7-r11)
__global__ __launch_bounds__(256) void wconv_kernel(
    const float* __restrict__ wqk, const float* __restrict__ sqk, const float* __restrict__ bqk,
    const float* __restrict__ wv,  const float* __restrict__ sv,  const float* __restrict__ bv,
    const float* __restrict__ wprj, const float* __restrict__ sprj,
    const float* __restrict__ wm1, const float* __restrict__ sm1, const float* __restrict__ bm1,
    const float* __restrict__ wm2, const float* __restrict__ sm2,
    unsigned short* __restrict__ Wqkv, unsigned short* __restrict__ Wp,
    unsigned short* __restrict__ Wm1,  unsigned short* __restrict__ Wm2,
    float* __restrict__ bpad, float* __restrict__ bqv)
{
    int i = blockIdx.x * 256 + threadIdx.x;
    if (i < 196608) {                       // Wqkv [768][256]
        int o = i >> 8, c = i & 255;
        float w;
        if (o < 512) { float f = ((o & 127) < 64) ? QSC : 1.f; w = wqk[i] * sqk[o] * f; }
        else          w = wv[(o - 512) * 256 + c] * sv[o - 512];
        Wqkv[i] = f2bf(w);
    } else if (i < 262144) {                // w_proj [256][256]
        int j = i - 196608; int o = j >> 8; Wp[j] = f2bf(wprj[j] * sprj[o]);
    } else if (i < 360448) {                // w_m1 [384pad][256]
        int j = i - 262144; int o = j >> 8, c = j & 255;
        Wm1[j] = (o < 307) ? f2bf(wm1[o * 256 + c] * sm1[o]) : (unsigned short)0;
    } else if (i < 458752) {                // w_m2 [256][384pad]
        int j = i - 360448; int o = j / 384, c = j - o * 384;
        Wm2[j] = (c < 307) ? f2bf(wm2[o * 307 + c] * sm2[o]) : (unsigned short)0;
    } else if (i < 459136) {                // b_m1 padded to 384
        int j = i - 458752; bpad[j] = (j < 307) ? bm1[j] : 0.f;
    } else if (i < 459904) {                // bqv[768]
        int j = i - 459136;
        bqv[j] = (j < 512) ? (bqk[j] * (((j & 127) < 64) ? QSC : 1.f)) : bv[j - 512];
    }
}

// Fused transpose + qkv GEMM; v also written transposed (unchanged, verified r11)
__global__ __launch_bounds__(256) void mmqkv_kernel(
    const float* __restrict__ X, const unsigned short* __restrict__ Wb,
    const float* __restrict__ bi, unsigned short* __restrict__ Yb,
    unsigned short* __restrict__ vT)
{
    __shared__ unsigned short Ap[64][40];
    __shared__ unsigned short Wt[128][40];
    const int tid = threadIdx.x, lane = tid & 63, wv = tid >> 6;
    const int lo4 = lane & 15, quad = lane >> 4;
    const int p0 = blockIdx.x * 64, o0 = blockIdx.y * 128, bB = blockIdx.z;
    const int ph = (wv & 1) * 32, oh = (wv >> 1) * 64;
    const int c2 = tid & 15, pg = tid >> 4;
    const int oW0 = tid >> 2, oW1 = (tid + 256) >> 2;
    const int cW = (tid & 3) * 8;
    const float* xb = X + (size_t)bB * 256 * 4096;

    f4v acc[4][2];
    #pragma unroll
    for (int i = 0; i < 4; i++)
        #pragma unroll
        for (int j = 0; j < 2; j++)
            acc[i][j] = (f4v){0.f, 0.f, 0.f, 0.f};

    float4 fa = *(const float4*)&xb[(size_t)(2 * c2) * 4096 + p0 + pg * 4];
    float4 fb = *(const float4*)&xb[(size_t)(2 * c2 + 1) * 4096 + p0 + pg * 4];
    uint4 wReg0 = *(const uint4*)(Wb + (size_t)(o0 + oW0) * 256 + cW);
    uint4 wReg1 = *(const uint4*)(Wb + (size_t)(o0 + oW1) * 256 + cW);

    for (int kc = 0; kc < 8; kc++) {
        __syncthreads();
        {
            float av[4] = {fa.x, fa.y, fa.z, fa.w};
            float bv2[4] = {fb.x, fb.y, fb.z, fb.w};
            #pragma unroll
            for (int i = 0; i < 4; i++)
                *(unsigned*)&Ap[pg * 4 + i][2 * c2] =
                    (unsigned)f2bf(av[i]) | ((unsigned)f2bf(bv2[i]) << 16);
        }
        *(uint4*)&Wt[oW0][cW] = wReg0;
        *(uint4*)&Wt[oW1][cW] = wReg1;
        __syncthreads();
        if (kc < 7) {
            int k1 = (kc + 1) * 32;
            fa = *(const float4*)&xb[(size_t)(k1 + 2 * c2) * 4096 + p0 + pg * 4];
            fb = *(const float4*)&xb[(size_t)(k1 + 2 * c2 + 1) * 4096 + p0 + pg * 4];
            wReg0 = *(const uint4*)(Wb + (size_t)(o0 + oW0) * 256 + k1 + cW);
            wReg1 = *(const uint4*)(Wb + (size_t)(o0 + oW1) * 256 + k1 + cW);
        }
        s8v af[4], bx[2];
        #pragma unroll
        for (int of = 0; of < 4; of++)
            af[of] = *(const s8v*)&Wt[oh + of * 16 + lo4][quad * 8];
        #pragma unroll
        for (int pf = 0; pf < 2; pf++)
            bx[pf] = *(const s8v*)&Ap[ph + pf * 16 + lo4][quad * 8];
        #pragma unroll
        for (int of = 0; of < 4; of++)
            #pragma unroll
            for (int pf = 0; pf < 2; pf++)
                acc[of][pf] = __builtin_amdgcn_mfma_f32_16x16x32_bf16(af[of], bx[pf], acc[of][pf], 0, 0, 0);
    }
    #pragma unroll
    for (int of = 0; of < 4; of++) {
        int ob = o0 + oh + of * 16 + quad * 4;
        float4 bb = *(const float4*)&bi[ob];
        float bbv[4] = {bb.x, bb.y, bb.z, bb.w};
        #pragma unroll
        for (int pf = 0; pf < 2; pf++) {
            int p = p0 + ph + pf * 16 + lo4;
            size_t row = (size_t)bB * 4096 + p;
            unsigned short b4[4];
            #pragma unroll
            for (int r = 0; r < 4; r++) b4[r] = f2bf(acc[of][pf][r] + bbv[r]);
            *(ushort4*)&Yb[row * 768 + ob] = *(ushort4*)b4;
            if (ob >= 512) {
                #pragma unroll
                for (int r = 0; r < 4; r++)
                    vT[((size_t)(bB * 256 + ob - 512 + r)) * 4096 + p] = b4[r];
            }
        }
    }
}

// MFMA area-attention (r11 structure + V-frag prefetch): barrier-free, direct-global
// Q/K/V frags, per-wave P LDS, ones-MFMA L, direct O stores, XCD swizzle.
__global__ __launch_bounds__(256) void attn_kernel(
    const unsigned short* __restrict__ qv, const unsigned short* __restrict__ vT,
    unsigned short* __restrict__ Opart, float* __restrict__ Lpart)
{
    __shared__ unsigned short Pq[4][32][72];   // per-wave P [q][m]
    const int tid = threadIdx.x;
    const int w = tid >> 6, lane = tid & 63;
    const int lo4 = lane & 15, quad = lane >> 4;
    const int n0 = blockIdx.z * 128;
    const int h = blockIdx.y;
    const int z = blockIdx.x;
    const int ba = z >> 2, spl = z & 3;
    const int bB = ba >> 2, g = ba & 3;
    const int mbase = spl * 256;

    s8v qf[2];
    #pragma unroll
    for (int qc = 0; qc < 2; qc++)
        qf[qc] = *(const s8v*)(qv + ((size_t)(bB * 4096 + quad * 1024 + n0 + w * 32 + qc * 16 + lo4)) * 768 + g * 128 + h * 8);
    const unsigned short* kbase = qv + ((size_t)(bB * 4096 + quad * 1024)) * 768 + g * 128 + 64 + h * 8;
    const int dd0 = lo4, dd1 = 16 + lo4;
    const unsigned short* vb0 = vT + ((size_t)(bB * 256 + g * 64 + h * 8 + (dd0 & 7))) * 4096 + (dd0 >> 3) * 1024 + mbase + quad * 8;
    const unsigned short* vb1 = vT + ((size_t)(bB * 256 + g * 64 + h * 8 + (dd1 & 7))) * 4096 + (dd1 >> 3) * 1024 + mbase + quad * 8;

    f4v oacc[2][2], Lacc[2];
    #pragma unroll
    for (int i = 0; i < 2; i++) {
        Lacc[i] = (f4v){0.f, 0.f, 0.f, 0.f};
        #pragma unroll
        for (int j = 0; j < 2; j++)
            oacc[i][j] = (f4v){0.f, 0.f, 0.f, 0.f};
    }
    s8v ones;
    #pragma unroll
    for (int j = 0; j < 8; j++) ones[j] = (short)0x3F80;   // bf16 1.0

    s8v kf[4], vReg[2][2];
    #pragma unroll
    for (int mf = 0; mf < 4; mf++)
        kf[mf] = *(const s8v*)(kbase + (size_t)(mbase + mf * 16 + lo4) * 768);
    #pragma unroll
    for (int mc = 0; mc < 2; mc++) {
        vReg[mc][0] = *(const s8v*)(vb0 + mc * 32);
        vReg[mc][1] = *(const s8v*)(vb1 + mc * 32);
    }

    for (int sc = 0; sc < 4; sc++) {
        s8v kfn[4], vNext[2][2];
        if (sc < 3) {
            #pragma unroll
            for (int mf = 0; mf < 4; mf++)
                kfn[mf] = *(const s8v*)(kbase + (size_t)(mbase + (sc + 1) * 64 + mf * 16 + lo4) * 768);
            #pragma unroll
            for (int mc = 0; mc < 2; mc++) {
                vNext[mc][0] = *(const s8v*)(vb0 + (sc + 1) * 64 + mc * 32);
                vNext[mc][1] = *(const s8v*)(vb1 + (sc + 1) * 64 + mc * 32);
            }
        }
        f4v sT[4][2];
        #pragma unroll
        for (int mf = 0; mf < 4; mf++)
            #pragma unroll
            for (int qc = 0; qc < 2; qc++)
                sT[mf][qc] = __builtin_amdgcn_mfma_f32_16x16x32_bf16(kf[mf], qf[qc], (f4v){0.f, 0.f, 0.f, 0.f}, 0, 0, 0);
        #pragma unroll
        for (int qc = 0; qc < 2; qc++) {
            #pragma unroll
            for (int mf = 0; mf < 4; mf++) {
                float p0v = exp2f(sT[mf][qc][0]);
                float p1v = exp2f(sT[mf][qc][1]);
                float p2v = exp2f(sT[mf][qc][2]);
                float p3v = exp2f(sT[mf][qc][3]);
                uint2 pk;
                pk.x = trunc2(p0v, p1v);
                pk.y = trunc2(p2v, p3v);
                *(uint2*)&Pq[w][qc * 16 + lo4][mf * 16 + quad * 4] = pk;
            }
        }
        #pragma unroll
        for (int mc = 0; mc < 2; mc++) {
            s8v pfr[2];
            #pragma unroll
            for (int qc = 0; qc < 2; qc++)
                pfr[qc] = *(const s8v*)&Pq[w][qc * 16 + lo4][mc * 32 + quad * 8];
            #pragma unroll
            for (int df = 0; df < 2; df++)
                #pragma unroll
                for (int qc = 0; qc < 2; qc++)
                    oacc[df][qc] = __builtin_amdgcn_mfma_f32_16x16x32_bf16(vReg[mc][df], pfr[qc], oacc[df][qc], 0, 0, 0);
            #pragma unroll
            for (int qc = 0; qc < 2; qc++)
                Lacc[qc] = __builtin_amdgcn_mfma_f32_16x16x32_bf16(ones, pfr[qc], Lacc[qc], 0, 0, 0);
        }
        #pragma unroll
        for (int mf = 0; mf < 4; mf++) kf[mf] = kfn[mf];
        #pragma unroll
        for (int mc = 0; mc < 2; mc++) {
            vReg[mc][0] = vNext[mc][0];
            vReg[mc][1] = vNext[mc][1];
        }
    }
    if (quad == 0) {
        size_t lb = (((size_t)(spl * 2 + bB) * 4 + g) * 8 + h) * 1024 + n0 + w * 32;
        Lpart[lb + lo4] = Lacc[0][0];
        Lpart[lb + 16 + lo4] = Lacc[1][0];
    }
    #pragma unroll
    for (int qc = 0; qc < 2; qc++)
        #pragma unroll
        for (int df = 0; df < 2; df++) {
            int pb = df * 2 + (quad >> 1);
            uint2 ov;
            ov.x = trunc2(oacc[df][qc][0], oacc[df][qc][1]);
            ov.y = trunc2(oacc[df][qc][2], oacc[df][qc][3]);
            *(uint2*)(Opart + ((size_t)(spl * 2 + bB) * 4096 + pb * 1024 + n0 + w * 32 + qc * 16 + lo4) * 256
                      + g * 64 + h * 8 + (quad & 1) * 4) = ov;
        }
}

// Fused combine + depthwise pe (unchanged, verified r8-r11)
__global__ __launch_bounds__(256) void attpe_kernel(
    const unsigned short* __restrict__ Opart, const float* __restrict__ Lpart,
    const unsigned short* __restrict__ qv, const float* __restrict__ wpe,
    const float* __restrict__ spe, const float* __restrict__ bpe,
    unsigned short* __restrict__ attpe)
{
    int idx = blockIdx.x * 256 + threadIdx.x;   // 2*4096*32
    int cg = (idx & 31) * 8;
    int p = (idx >> 5) & 4095;
    int bB = idx >> 17;
    int g = cg >> 6, h = (cg >> 3) & 7;
    int na = p & 1023;
    float L = 0.f;
    float o[8] = {};
    #pragma unroll
    for (int spl = 0; spl < 4; spl++) {
        L += Lpart[(((size_t)(spl * 2 + bB) * 4 + g) * 8 + h) * 1024 + na];
        uint4 v = *(const uint4*)(Opart + ((size_t)(spl * 2 + bB) * 4096 + p) * 256 + cg);
        unsigned short tmp[8]; *(uint4*)tmp = v;
        #pragma unroll
        for (int j = 0; j < 8; j++) o[j] += bf2f(tmp[j]);
    }
    float inv = 1.f / L;
    int hh = p >> 6, ww = p & 63;
    float pe[8] = {};
    for (int di = -1; di <= 1; di++) {
        int h2 = hh + di;
        if (h2 < 0 || h2 > 63) continue;
        for (int dj = -1; dj <= 1; dj++) {
            int w2 = ww + dj;
            if (w2 < 0 || w2 > 63) continue;
            uint4 vv = *(const uint4*)(qv + ((size_t)(bB * 4096 + h2 * 64 + w2)) * 768 + 512 + cg);
            unsigned short tmp[8]; *(uint4*)tmp = vv;
            int k = (di + 1) * 3 + (dj + 1);
            #pragma unroll
            for (int j = 0; j < 8; j++)
                pe[j] = fmaf(bf2f(tmp[j]), wpe[(cg + j) * 9 + k], pe[j]);
        }
    }
    unsigned short ob[8];
    #pragma unroll
    for (int j = 0; j < 8; j++)
        ob[j] = f2bf(o[j] * inv + pe[j] * spe[cg + j] + bpe[cg + j]);
    *(uint4*)(attpe + ((size_t)(bB * 4096 + p)) * 256 + cg) = *(uint4*)ob;
}

// Fused proj+m1+m2: block owns 32 positions end-to-end. Activations LDS-resident;
// weights consumed as direct-global 16B A-frags (no W staging, 3 barriers total).
// Fragment conventions identical to the verified mm (D rows = o, cols = p).
__global__ __launch_bounds__(256) void mlp3_kernel(
    const unsigned short* __restrict__ attpe, const float* __restrict__ x,
    const unsigned short* __restrict__ Wp, const float* __restrict__ bp,
    const unsigned short* __restrict__ Wm1, const float* __restrict__ bm1p,
    const unsigned short* __restrict__ Wm2, const float* __restrict__ bm2,
    float* __restrict__ out)
{
    __shared__ unsigned short bufA[32][392];  // [p][c]: attpe(256) then mh(384)
    __shared__ unsigned short bufX[32][264];  // [p][o]: x1 bf16
    const int tid = threadIdx.x, lane = tid & 63, wv = tid >> 6;
    const int lo4 = lane & 15, quad = lane >> 4;
    const int p0 = blockIdx.x * 32, bB = blockIdx.y;

    {   // stage attpe tile [32p][256c]
        int row = tid >> 3, cb = (tid & 7) * 32;
        const unsigned short* src = attpe + ((size_t)(bB * 4096 + p0 + row)) * 256 + cb;
        #pragma unroll
        for (int i = 0; i < 4; i++)
            *(uint4*)&bufA[row][cb + i * 8] = *(const uint4*)(src + i * 8);
    }
    __syncthreads();

    // ---- stage 1: x1 = x + proj(attpe); wave o-range wv*64..+63, K=256
    {
        f4v acc[4][2];
        #pragma unroll
        for (int i = 0; i < 4; i++)
            #pragma unroll
            for (int j = 0; j < 2; j++) acc[i][j] = (f4v){0.f, 0.f, 0.f, 0.f};
        for (int kk = 0; kk < 8; kk++) {
            s8v bx[2];
            #pragma unroll
            for (int pf = 0; pf < 2; pf++)
                bx[pf] = *(const s8v*)&bufA[pf * 16 + lo4][kk * 32 + quad * 8];
            #pragma unroll
            for (int of = 0; of < 4; of++) {
                s8v af = *(const s8v*)(Wp + (size_t)(wv * 64 + of * 16 + lo4) * 256 + kk * 32 + quad * 8);
                #pragma unroll
                for (int pf = 0; pf < 2; pf++)
                    acc[of][pf] = __builtin_amdgcn_mfma_f32_16x16x32_bf16(af, bx[pf], acc[of][pf], 0, 0, 0);
            }
        }
        #pragma unroll
        for (int of = 0; of < 4; of++) {
            int ob = wv * 64 + of * 16 + quad * 4;
            float4 bb = *(const float4*)&bp[ob];
            float bbv[4] = {bb.x, bb.y, bb.z, bb.w};
            #pragma unroll
            for (int pf = 0; pf < 2; pf++) {
                int p = p0 + pf * 16 + lo4;
                unsigned short b4[4];
                #pragma unroll
                for (int r = 0; r < 4; r++) {
                    float y = acc[of][pf][r] + bbv[r] + x[((size_t)(bB * 256 + ob + r)) * 4096 + p];
                    b4[r] = f2bf(y);
                }
                *(ushort4*)&bufX[pf * 16 + lo4][ob] = *(ushort4*)b4;
            }
        }
    }
    __syncthreads();

    // ---- stage 2: mh = silu(m1(x1)); wave o-range wv*96..+95 (6 of), K=256
    {
        f4v acc[6][2];
        #pragma unroll
        for (int i = 0; i < 6; i++)
            #pragma unroll
            for (int j = 0; j < 2; j++) acc[i][j] = (f4v){0.f, 0.f, 0.f, 0.f};
        for (int kk = 0; kk < 8; kk++) {
            s8v bx[2];
            #pragma unroll
            for (int pf = 0; pf < 2; pf++)
                bx[pf] = *(const s8v*)&bufX[pf * 16 + lo4][kk * 32 + quad * 8];
            #pragma unroll
            for (int of = 0; of < 6; of++) {
                s8v af = *(const s8v*)(Wm1 + (size_t)(wv * 96 + of * 16 + lo4) * 256 + kk * 32 + quad * 8);
                #pragma unroll
                for (int pf = 0; pf < 2; pf++)
                    acc[of][pf] = __builtin_amdgcn_mfma_f32_16x16x32_bf16(af, bx[pf], acc[of][pf], 0, 0, 0);
            }
        }
        #pragma unroll
        for (int of = 0; of < 6; of++) {
            int ob = wv * 96 + of * 16 + quad * 4;
            float4 bb = *(const float4*)&bm1p[ob];
            float bbv[4] = {bb.x, bb.y, bb.z, bb.w};
            #pragma unroll
            for (int pf = 0; pf < 2; pf++) {
                unsigned short b4[4];
                #pragma unroll
                for (int r = 0; r < 4; r++) {
                    float y = acc[of][pf][r] + bbv[r];
                    y = y / (1.f + __expf(-y));
                    b4[r] = f2bf(y);
                }
                *(ushort4*)&bufA[pf * 16 + lo4][ob] = *(ushort4*)b4;
            }
        }
    }
    __syncthreads();

    // ---- stage 3: out = x1 + m2(mh); wave o-range wv*64..+63, K=384, transposed stores
    {
        f4v acc[4][2];
        #pragma unroll
        for (int i = 0; i < 4; i++)
            #pragma unroll
            for (int j = 0; j < 2; j++) acc[i][j] = (f4v){0.f, 0.f, 0.f, 0.f};
        for (int kk = 0; kk < 12; kk++) {
            s8v bx[2];
            #pragma unroll
            for (int pf = 0; pf < 2; pf++)
                bx[pf] = *(const s8v*)&bufA[pf * 16 + lo4][kk * 32 + quad * 8];
            #pragma unroll
            for (int of = 0; of < 4; of++) {
                s8v af = *(const s8v*)(Wm2 + (size_t)(wv * 64 + of * 16 + lo4) * 384 + kk * 32 + quad * 8);
                #pragma unroll
                for (int pf = 0; pf < 2; pf++)
                    acc[of][pf] = __builtin_amdgcn_mfma_f32_16x16x32_bf16(af, bx[pf], acc[of][pf], 0, 0, 0);
            }
        }
        #pragma unroll
        for (int of = 0; of < 4; of++) {
            int ob = wv * 64 + of * 16 + quad * 4;
            float4 bb = *(const float4*)&bm2[ob];
            float bbv[4] = {bb.x, bb.y, bb.z, bb.w};
            #pragma unroll
            for (int pf = 0; pf < 2; pf++) {
                int p = p0 + pf * 16 + lo4;
                ushort4 x1v = *(const ushort4*)&bufX[pf * 16 + lo4][ob];
                unsigned short x1a[4]; *(ushort4*)x1a = x1v;
                #pragma unroll
                for (int r = 0; r < 4; r++) {
                    float y = acc[of][pf][r] + bbv[r] + bf2f(x1a[r]);
                    out[((size_t)(bB * 256 + ob + r)) * 4096 + p] = y;
                }
            }
        }
    }
}

extern "C" void kernel_launch(void* const* d_in, const int* in_sizes, int n_in,
                              void* d_out, int out_size, void* d_ws, size_t ws_size,
                              hipStream_t stream)
{
    const float* x      = (const float*)d_in[0];
    const float* w_qk   = (const float*)d_in[1];
    const float* s_qk   = (const float*)d_in[2];
    const float* b_qk   = (const float*)d_in[3];
    const float* w_v    = (const float*)d_in[4];
    const float* s_v    = (const float*)d_in[5];
    const float* b_v    = (const float*)d_in[6];
    const float* w_pe   = (const float*)d_in[7];
    const float* s_pe   = (const float*)d_in[8];
    const float* b_pe   = (const float*)d_in[9];
    const float* w_proj = (const float*)d_in[10];
    const float* s_proj = (const float*)d_in[11];
    const float* b_proj = (const float*)d_in[12];
    const float* w_m1   = (const float*)d_in[13];
    const float* s_m1   = (const float*)d_in[14];
    const float* b_m1   = (const float*)d_in[15];
    const float* w_m2   = (const float*)d_in[16];
    const float* s_m2   = (const float*)d_in[17];
    const float* b_m2   = (const float*)d_in[18];
    float* out = (float*)d_out;

    const size_t NA = (size_t)2 * 4096 * 256;     // 2,097,152
    unsigned short* attpe = (unsigned short*)d_ws;  // bf16 [b][p][256]
    unsigned short* qv   = attpe + NA;            // bf16 [b][p][768]
    unsigned short* Opart = qv + 3 * NA;          // bf16 [4][b][p][256]
    float* Lpart = (float*)(Opart + 4 * NA);      // fp32 [4][b][4][8][1024]
    unsigned short* Wqkv = (unsigned short*)(Lpart + 262144);
    unsigned short* Wp   = Wqkv + 196608;
    unsigned short* Wm1  = Wp + 65536;
    unsigned short* Wm2  = Wm1 + 98304;
    float* bpad = (float*)(Wm2 + 98304);
    float* bqv  = bpad + 384;
    unsigned short* vT = (unsigned short*)(bqv + 768);   // bf16 [b][256][4096]

    dim3 blk(256);
    wconv_kernel<<<dim3(1797), blk, 0, stream>>>(
        w_qk, s_qk, b_qk, w_v, s_v, b_v, w_proj, s_proj,
        w_m1, s_m1, b_m1, w_m2, s_m2, Wqkv, Wp, Wm1, Wm2, bpad, bqv);

    mmqkv_kernel<<<dim3(64, 6, 2), blk, 0, stream>>>(x, Wqkv, bqv, qv, vT);

    attn_kernel<<<dim3(32, 8, 8), blk, 0, stream>>>(qv, vT, Opart, Lpart);
    attpe_kernel<<<dim3(1024), blk, 0, stream>>>(Opart, Lpart, qv, w_pe, s_pe, b_pe, attpe);

    // fused proj + m1 + m2 (+ both residuals), out stored transposed fp32
    mlp3_kernel<<<dim3(128, 2), blk, 0, stream>>>(
        attpe, x, Wp, b_proj, Wm1, bpad, Wm2, b_m2, out);
}